// Round 1
// baseline (1396.765 us; speedup 1.0000x reference)
//
#include <hip/hip_runtime.h>

#define N_NODES   100000
#define N_EDGES   1600000
#define F_IN      10
#define HD        128
#define N_LAYERS  3
#define N_GRAPHS  256
#define N_CLASSES 25
#define BN_EPS    1e-5f
#define POOL_TILE 256

// ---------------- graph build ----------------

__global__ void k_degree(const int* __restrict__ rows, int* __restrict__ degi, int e){
    int i = blockIdx.x*blockDim.x + threadIdx.x;
    if (i < e) atomicAdd(&degi[rows[i]], 1);
}

__global__ void k_dinv(const int* __restrict__ degi, float* __restrict__ dinv, int n){
    int i = blockIdx.x*blockDim.x + threadIdx.x;
    if (i < n) dinv[i] = rsqrtf((float)(degi[i] + 1));   // +1 self loop
}

// exclusive scan of in-degree counts -> rowptr (3-pass)
__global__ void k_scan1(const int* __restrict__ cnt, int* __restrict__ excl,
                        int* __restrict__ bsums, int n){
    __shared__ int s[1024];
    int tid = threadIdx.x;
    int i = blockIdx.x*1024 + tid;
    int v = (i < n) ? cnt[i] : 0;
    s[tid] = v;
    __syncthreads();
    for (int d = 1; d < 1024; d <<= 1){
        int t = (tid >= d) ? s[tid-d] : 0;
        __syncthreads();
        s[tid] += t;
        __syncthreads();
    }
    if (i < n) excl[i] = s[tid] - v;
    if (tid == 0) bsums[blockIdx.x] = s[1023];
}

__global__ void k_scan2(int* bsums, int nb){
    if (threadIdx.x == 0 && blockIdx.x == 0){
        int run = 0;
        for (int b = 0; b < nb; b++){ int t = bsums[b]; bsums[b] = run; run += t; }
    }
}

__global__ void k_scan3(int* __restrict__ rowptr, const int* __restrict__ bsums,
                        int* __restrict__ cursor, int n, int etot){
    int i = blockIdx.x*1024 + threadIdx.x;
    if (i < n){
        int v = rowptr[i] + bsums[blockIdx.x];
        rowptr[i] = v;
        cursor[i] = v;
    }
    if (i == 0) rowptr[n] = etot;
}

__global__ void k_fill(const int* __restrict__ rows, const int* __restrict__ cols,
                       int* __restrict__ cursor, int* __restrict__ colidx, int e){
    int i = blockIdx.x*blockDim.x + threadIdx.x;
    if (i < e){
        int r = rows[i];
        int pos = atomicAdd(&cursor[r], 1);
        colidx[pos] = cols[i];
    }
}

// ---------------- input projection: h = relu(x @ Wp + bp) ----------------
__global__ void k_proj(const float* __restrict__ x, const float* __restrict__ Wp,
                       const float* __restrict__ bp, float* __restrict__ h, int n){
    __shared__ float sW[F_IN*HD];
    __shared__ float sb[HD];
    for (int t = threadIdx.x; t < F_IN*HD; t += 256) sW[t] = Wp[t];
    if (threadIdx.x < HD) sb[threadIdx.x] = bp[threadIdx.x];
    __syncthreads();
    int j  = threadIdx.x & (HD-1);
    int ln = threadIdx.x >> 7;      // 0..1, two nodes per block-iter
    for (int n0 = blockIdx.x*2 + ln; n0 < n; n0 += gridDim.x*2){
        float acc = sb[j];
        #pragma unroll
        for (int k = 0; k < F_IN; k++) acc += x[(size_t)n0*F_IN + k] * sW[k*HD + j];
        h[(size_t)n0*HD + j] = fmaxf(acc, 0.f);
    }
}

// ---------------- layer GEMM: hw = (h @ Wc) * dinv[row] ----------------
// block 256, 64-row tiles, Wc (64KB) + padded h-tile (64x132, kills the
// 4-way bank conflict a stride-128 row layout would have) in dynamic LDS.
__global__ __launch_bounds__(256) void k_gemm(const float* __restrict__ h,
        const float* __restrict__ W, const float* __restrict__ dinv,
        float* __restrict__ hw, int n){
    extern __shared__ float sm[];
    float* Ws = sm;               // 128*128
    float* hs = sm + HD*HD;       // 64*132
    const float4* W4 = (const float4*)W;
    float4* Ws4 = (float4*)Ws;
    for (int t = threadIdx.x; t < HD*HD/4; t += 256) Ws4[t] = W4[t];

    int ntiles = (n + 63) >> 6;
    int tc = (threadIdx.x & 15) * 8;   // 8 cols per thread
    int tr = (threadIdx.x >> 4) * 4;   // 4 rows per thread
    for (int tile = blockIdx.x; tile < ntiles; tile += gridDim.x){
        int row0 = tile << 6;
        for (int t = threadIdx.x; t < 64*32; t += 256){
            int r = t >> 5, c4 = t & 31;
            float4 v = make_float4(0.f, 0.f, 0.f, 0.f);
            if (row0 + r < n) v = ((const float4*)h)[(size_t)(row0+r)*32 + c4];
            *(float4*)&hs[r*132 + c4*4] = v;
        }
        __syncthreads();

        float acc[4][8] = {};
        #pragma unroll 4
        for (int k = 0; k < HD; k++){
            float a[4];
            a[0] = hs[(tr+0)*132 + k];
            a[1] = hs[(tr+1)*132 + k];
            a[2] = hs[(tr+2)*132 + k];
            a[3] = hs[(tr+3)*132 + k];
            float4 b0 = *(const float4*)&Ws[k*HD + tc];
            float4 b1 = *(const float4*)&Ws[k*HD + tc + 4];
            float b[8] = {b0.x,b0.y,b0.z,b0.w,b1.x,b1.y,b1.z,b1.w};
            #pragma unroll
            for (int m = 0; m < 4; m++)
                #pragma unroll
                for (int q = 0; q < 8; q++) acc[m][q] += a[m]*b[q];
        }

        #pragma unroll
        for (int m = 0; m < 4; m++){
            int row = row0 + tr + m;
            if (row < n){
                float dv = dinv[row];
                float4 o0 = make_float4(acc[m][0]*dv, acc[m][1]*dv, acc[m][2]*dv, acc[m][3]*dv);
                float4 o1 = make_float4(acc[m][4]*dv, acc[m][5]*dv, acc[m][6]*dv, acc[m][7]*dv);
                *(float4*)&hw[(size_t)row*HD + tc]     = o0;
                *(float4*)&hw[(size_t)row*HD + tc + 4] = o1;
            }
        }
        __syncthreads();
    }
}

// ---------------- aggregation + bias + BN + relu ----------------
// one wave per node, lane holds float2 (2 features). hw already carries
// dinv[col]; multiply the sum (incl. self term) by dinv[row].
__global__ void k_agg(const float* __restrict__ hw, const int* __restrict__ rowptr,
        const int* __restrict__ colidx, const float* __restrict__ dinv,
        const float* __restrict__ bc, const float* __restrict__ bmean,
        const float* __restrict__ bvar, const float* __restrict__ bgamma,
        const float* __restrict__ bbeta, float* __restrict__ hout, int n){
    int node = blockIdx.x*4 + (threadIdx.x >> 6);
    int lane = threadIdx.x & 63;
    if (node >= n) return;
    const float2* hw2 = (const float2*)hw;
    float2 acc = hw2[(size_t)node*64 + lane];          // self loop term
    int s = rowptr[node], e = rowptr[node+1];
    for (int t = s; t < e; t++){
        int c = colidx[t];
        float2 v = hw2[(size_t)c*64 + lane];
        acc.x += v.x; acc.y += v.y;
    }
    float dv = dinv[node];
    float2 cb  = ((const float2*)bc)[lane];
    float2 cm  = ((const float2*)bmean)[lane];
    float2 cv  = ((const float2*)bvar)[lane];
    float2 cg  = ((const float2*)bgamma)[lane];
    float2 cbe = ((const float2*)bbeta)[lane];
    float ax = acc.x*dv + cb.x;
    float ay = acc.y*dv + cb.y;
    ax = (ax - cm.x) * rsqrtf(cv.x + BN_EPS) * cg.x + cbe.x;
    ay = (ay - cm.y) * rsqrtf(cv.y + BN_EPS) * cg.y + cbe.y;
    ((float2*)hout)[(size_t)node*64 + lane] = make_float2(fmaxf(ax,0.f), fmaxf(ay,0.f));
}

// ---------------- pooling ----------------
__global__ void k_count(const int* __restrict__ batch, int* __restrict__ gcnt, int n){
    int i = blockIdx.x*blockDim.x + threadIdx.x;
    if (i < n) atomicAdd(&gcnt[batch[i]], 1);
}

// batch is sorted: per-block run-length local reduce, flush on graph change.
// h >= 0 (post-relu) so float max == int max on the bit pattern, init 0.
__global__ void k_pool(const float* __restrict__ h, const int* __restrict__ batch,
        float* __restrict__ gsum, int* __restrict__ gmax, int n){
    int f = threadIdx.x;   // 128 threads = feature
    int start = blockIdx.x * POOL_TILE;
    int end = min(start + POOL_TILE, n);
    if (start >= end) return;
    int cur = batch[start];
    float s = 0.f, mx = 0.f;
    for (int i = start; i < end; i++){
        int b = batch[i];
        float v = h[(size_t)i*HD + f];
        if (b != cur){
            atomicAdd(&gsum[cur*HD+f], s);
            atomicMax(&gmax[cur*HD+f], __float_as_int(mx));
            s = 0.f; mx = 0.f; cur = b;
        }
        s += v; mx = fmaxf(mx, v);
    }
    atomicAdd(&gsum[cur*HD+f], s);
    atomicMax(&gmax[cur*HD+f], __float_as_int(mx));
}

// ---------------- head MLP ----------------
__global__ void k_mlp1(const float* __restrict__ gsum, const int* __restrict__ gmax,
        const int* __restrict__ gcnt, const float* __restrict__ W1,
        const float* __restrict__ b1, float* __restrict__ hidden){
    __shared__ float gv[2*HD];
    int g = blockIdx.x, j = threadIdx.x;
    float denom = (float)max(gcnt[g], 1);
    gv[j]    = gsum[g*HD+j] / denom;
    gv[HD+j] = __int_as_float(gmax[g*HD+j]);   // 0 for empty graphs (matches guard)
    __syncthreads();
    float acc = b1[j];
    #pragma unroll 8
    for (int k = 0; k < 2*HD; k++) acc += gv[k]*W1[k*HD + j];
    hidden[g*HD + j] = fmaxf(acc, 0.f);
}

__global__ void k_mlp2(const float* __restrict__ hidden, const float* __restrict__ W2,
        const float* __restrict__ b2, float* __restrict__ out){
    int g = blockIdx.x, c = threadIdx.x;
    if (c >= N_CLASSES) return;
    float acc = b2[c];
    #pragma unroll 4
    for (int j = 0; j < HD; j++) acc += hidden[g*HD + j]*W2[j*N_CLASSES + c];
    out[g*N_CLASSES + c] = acc;
}

// ---------------- launch ----------------
extern "C" void kernel_launch(void* const* d_in, const int* in_sizes, int n_in,
                              void* d_out, int out_size, void* d_ws, size_t ws_size,
                              hipStream_t stream){
    const float* x   = (const float*)d_in[0];
    const int*  eidx = (const int*)d_in[1];
    const int* batch = (const int*)d_in[2];
    const float* Wp  = (const float*)d_in[3];
    const float* bp  = (const float*)d_in[4];
    const float* Wc  = (const float*)d_in[5];
    const float* bc  = (const float*)d_in[6];
    const float* bng = (const float*)d_in[7];
    const float* bnb = (const float*)d_in[8];
    const float* bnm = (const float*)d_in[9];
    const float* bnv = (const float*)d_in[10];
    const float* W1  = (const float*)d_in[11];
    const float* b1  = (const float*)d_in[12];
    const float* W2  = (const float*)d_in[13];
    const float* b2  = (const float*)d_in[14];
    float* out = (float*)d_out;

    // workspace layout (~106 MB total)
    char* ws = (char*)d_ws;
    size_t off = 0;
    float* h      = (float*)(ws + off); off += (size_t)N_NODES*HD*4;   // 51.2 MB
    float* hw     = (float*)(ws + off); off += (size_t)N_NODES*HD*4;   // 51.2 MB
    float* dinv   = (float*)(ws + off); off += (size_t)N_NODES*4;
    int*   degi   = (int*)  (ws + off); off += (size_t)N_NODES*4;
    int*   rowptr = (int*)  (ws + off); off += (size_t)(N_NODES+16)*4;
    int*   cursor = (int*)  (ws + off); off += (size_t)N_NODES*4;
    int*   colidx = (int*)  (ws + off); off += (size_t)N_EDGES*4;      // 6.4 MB
    int*   bsums  = (int*)  (ws + off); off += 512;
    float* gsum   = (float*)(ws + off); off += (size_t)N_GRAPHS*HD*4;
    int*   gmax   = (int*)  (ws + off); off += (size_t)N_GRAPHS*HD*4;
    int*   gcnt   = (int*)  (ws + off); off += 1024;
    float* hidden = (float*)(ws + off); off += (size_t)N_GRAPHS*HD*4;

    const int* rows = eidx;             // targets (aggregation index)
    const int* cols = eidx + N_EDGES;   // sources (gather index)

    hipMemsetAsync(degi, 0, (size_t)N_NODES*4, stream);
    hipMemsetAsync(gsum, 0, (size_t)(N_GRAPHS*HD*2)*4 + 1024, stream);  // gsum+gmax+gcnt

    k_degree<<<N_EDGES/256, 256, 0, stream>>>(rows, degi, N_EDGES);
    k_dinv<<<(N_NODES+255)/256, 256, 0, stream>>>(degi, dinv, N_NODES);
    int nb = (N_NODES + 1023)/1024;
    k_scan1<<<nb, 1024, 0, stream>>>(degi, rowptr, bsums, N_NODES);
    k_scan2<<<1, 64, 0, stream>>>(bsums, nb);
    k_scan3<<<nb, 1024, 0, stream>>>(rowptr, bsums, cursor, N_NODES, N_EDGES);
    k_fill<<<N_EDGES/256, 256, 0, stream>>>(rows, cols, cursor, colidx, N_EDGES);

    k_proj<<<1024, 256, 0, stream>>>(x, Wp, bp, h, N_NODES);

    size_t shmem = (size_t)(HD*HD + 64*132)*4;   // 99,328 B dynamic LDS
    for (int l = 0; l < N_LAYERS; l++){
        k_gemm<<<512, 256, shmem, stream>>>(h, Wc + (size_t)l*HD*HD, dinv, hw, N_NODES);
        k_agg<<<(N_NODES+3)/4, 256, 0, stream>>>(hw, rowptr, colidx, dinv,
            bc + l*HD, bnm + l*HD, bnv + l*HD, bng + l*HD, bnb + l*HD, h, N_NODES);
    }

    k_count<<<(N_NODES+255)/256, 256, 0, stream>>>(batch, gcnt, N_NODES);
    k_pool<<<(N_NODES+POOL_TILE-1)/POOL_TILE, 128, 0, stream>>>(h, batch, gsum, gmax, N_NODES);
    k_mlp1<<<N_GRAPHS, 128, 0, stream>>>(gsum, gmax, gcnt, W1, b1, hidden);
    k_mlp2<<<N_GRAPHS, 32, 0, stream>>>(hidden, W2, b2, out);
}

// Round 2
// 780.960 us; speedup vs baseline: 1.7885x; 1.7885x over previous
//
#include <hip/hip_runtime.h>

#define N_NODES   100000
#define N_EDGES   1600000
#define F_IN      10
#define HD        128
#define N_LAYERS  3
#define N_GRAPHS  256
#define N_CLASSES 25
#define BN_EPS    1e-5f
#define POOL_TILE 64
#define LDS_PITCH 152   // shorts; 304 B row stride: 16B-aligned, 2-way bank conflict max

typedef __attribute__((ext_vector_type(8))) short bf8;
typedef __attribute__((ext_vector_type(4))) float f32x4;

static __device__ __forceinline__ unsigned short f2bf(float f){
    unsigned u = __float_as_uint(f);
    unsigned r = (u + 0x7fffu + ((u >> 16) & 1u)) >> 16;
    return (unsigned short)r;
}
static __device__ __forceinline__ float bflo(unsigned u){ return __uint_as_float(u << 16); }
static __device__ __forceinline__ float bfhi(unsigned u){ return __uint_as_float(u & 0xffff0000u); }
static __device__ __forceinline__ unsigned packbf(float a, float b){
    return (unsigned)f2bf(a) | ((unsigned)f2bf(b) << 16);
}

// ---------------- graph build ----------------

__global__ void k_degree(const int* __restrict__ rows, int* __restrict__ degi, int e){
    int i = blockIdx.x*blockDim.x + threadIdx.x;
    if (i < e) atomicAdd(&degi[rows[i]], 1);
}

__global__ void k_dinv(const int* __restrict__ degi, float* __restrict__ dinv, int n){
    int i = blockIdx.x*blockDim.x + threadIdx.x;
    if (i < n) dinv[i] = rsqrtf((float)(degi[i] + 1));   // +1 self loop
}

__global__ void k_scan1(const int* __restrict__ cnt, int* __restrict__ excl,
                        int* __restrict__ bsums, int n){
    __shared__ int s[1024];
    int tid = threadIdx.x;
    int i = blockIdx.x*1024 + tid;
    int v = (i < n) ? cnt[i] : 0;
    s[tid] = v;
    __syncthreads();
    for (int d = 1; d < 1024; d <<= 1){
        int t = (tid >= d) ? s[tid-d] : 0;
        __syncthreads();
        s[tid] += t;
        __syncthreads();
    }
    if (i < n) excl[i] = s[tid] - v;
    if (tid == 0) bsums[blockIdx.x] = s[1023];
}

// parallel single-block exclusive scan of block sums (nb <= 128)
__global__ void k_scan2(int* bsums, int nb){
    __shared__ int s[128];
    int tid = threadIdx.x;
    int v = (tid < nb) ? bsums[tid] : 0;
    s[tid] = v;
    __syncthreads();
    for (int d = 1; d < 128; d <<= 1){
        int t = (tid >= d) ? s[tid-d] : 0;
        __syncthreads();
        s[tid] += t;
        __syncthreads();
    }
    if (tid < nb) bsums[tid] = s[tid] - v;
}

__global__ void k_scan3(int* __restrict__ rowptr, const int* __restrict__ bsums,
                        int* __restrict__ cursor, int n, int etot){
    int i = blockIdx.x*1024 + threadIdx.x;
    if (i < n){
        int v = rowptr[i] + bsums[blockIdx.x];
        rowptr[i] = v;
        cursor[i] = v;
    }
    if (i == 0) rowptr[n] = etot;
}

__global__ void k_fill(const int* __restrict__ rows, const int* __restrict__ cols,
                       int* __restrict__ cursor, int* __restrict__ colidx, int e){
    int i = blockIdx.x*blockDim.x + threadIdx.x;
    if (i < e){
        int r = rows[i];
        int pos = atomicAdd(&cursor[r], 1);
        colidx[pos] = cols[i];
    }
}

// ---------------- weight transpose+cast: WT[l][n][k] bf16 ----------------
__global__ void k_prepW(const float* __restrict__ Wc, unsigned short* __restrict__ WT){
    int i = blockIdx.x*256 + threadIdx.x;      // over L*128*128
    int l = i >> 14;
    int r = (i >> 7) & 127;                    // k
    int c = i & 127;                           // n
    WT[(l << 14) + c*HD + r] = f2bf(Wc[i]);
}

// ---------------- input projection: h = relu(x @ Wp + bp), bf16 out ----------------
__global__ void k_proj(const float* __restrict__ x, const float* __restrict__ Wp,
                       const float* __restrict__ bp, unsigned* __restrict__ hbf, int n){
    __shared__ float sW[F_IN*HD];
    __shared__ float sb[HD];
    for (int t = threadIdx.x; t < F_IN*HD; t += 256) sW[t] = Wp[t];
    if (threadIdx.x < HD) sb[threadIdx.x] = bp[threadIdx.x];
    __syncthreads();
    int j  = threadIdx.x & 63;      // feature pair
    int ln = threadIdx.x >> 6;      // 4 nodes per block-iter
    for (int n0 = blockIdx.x*4 + ln; n0 < n; n0 += gridDim.x*4){
        float a0 = sb[2*j], a1 = sb[2*j+1];
        #pragma unroll
        for (int k = 0; k < F_IN; k++){
            float xv = x[(size_t)n0*F_IN + k];
            a0 += xv * sW[k*HD + 2*j];
            a1 += xv * sW[k*HD + 2*j+1];
        }
        hbf[(size_t)n0*64 + j] = packbf(fmaxf(a0, 0.f), fmaxf(a1, 0.f));
    }
}

// ---------------- layer GEMM (bf16 MFMA): hw = bf16((h @ Wc) * dinv[row]) ----------------
// 128-row tile per block; K=128 and B^T fully LDS-resident. Wave = 32 rows x 128 cols
// = 2x8 tiles of 16x16x32 MFMA, 64 f32 acc regs.
// A frag: row=lane&15, k=quad*8+j (m120-verified). B^T frag: col=lane&15, same k (m97).
// C/D: col=lane&15, row=quad*4+reg (m89/m91-verified).
__global__ __launch_bounds__(256) void k_gemm(const unsigned short* __restrict__ hbf,
        const unsigned short* __restrict__ WT, const float* __restrict__ dinv,
        unsigned short* __restrict__ hw, int n){
    extern __shared__ char smem[];
    unsigned short* As = (unsigned short*)smem;            // 128 x LDS_PITCH
    unsigned short* Bs = As + 128*LDS_PITCH;               // 128 x LDS_PITCH
    int tid = threadIdx.x;
    int row0 = blockIdx.x * 128;

    const uint4* h4 = (const uint4*)hbf;
    const uint4* w4 = (const uint4*)WT;
    #pragma unroll
    for (int q = tid; q < 2048; q += 256){                 // 128 rows x 16 chunks of 16B
        int r = q >> 4, c = q & 15;
        uint4 v = make_uint4(0u,0u,0u,0u);
        if (row0 + r < n) v = h4[(size_t)(row0 + r)*16 + c];
        *(uint4*)&As[r*LDS_PITCH + c*8] = v;
        *(uint4*)&Bs[r*LDS_PITCH + c*8] = w4[r*16 + c];
    }
    __syncthreads();

    int w = tid >> 6, lane = tid & 63;
    int l15 = lane & 15, quad = lane >> 4;
    f32x4 acc[2][8];
    #pragma unroll
    for (int rt = 0; rt < 2; rt++)
        #pragma unroll
        for (int ct = 0; ct < 8; ct++) acc[rt][ct] = (f32x4){0.f,0.f,0.f,0.f};

    int arow = w*32 + l15;
    #pragma unroll
    for (int kc = 0; kc < 4; kc++){
        int ko = kc*32 + quad*8;
        bf8 a0 = *(const bf8*)&As[arow*LDS_PITCH + ko];
        bf8 a1 = *(const bf8*)&As[(arow+16)*LDS_PITCH + ko];
        #pragma unroll
        for (int ct = 0; ct < 8; ct++){
            bf8 b = *(const bf8*)&Bs[(ct*16 + l15)*LDS_PITCH + ko];
            acc[0][ct] = __builtin_amdgcn_mfma_f32_16x16x32_bf16(a0, b, acc[0][ct], 0, 0, 0);
            acc[1][ct] = __builtin_amdgcn_mfma_f32_16x16x32_bf16(a1, b, acc[1][ct], 0, 0, 0);
        }
    }

    #pragma unroll
    for (int rt = 0; rt < 2; rt++){
        #pragma unroll
        for (int reg = 0; reg < 4; reg++){
            int row = row0 + w*32 + rt*16 + quad*4 + reg;
            if (row < n){
                float dv = dinv[row];
                #pragma unroll
                for (int ct = 0; ct < 8; ct++){
                    hw[(size_t)row*HD + ct*16 + l15] = f2bf(acc[rt][ct][reg] * dv);
                }
            }
        }
    }
}

// ---------------- aggregation + bias + BN + relu ----------------
// one wave per node; lane holds bf16x2 (4 B) -> 256 B coalesced row gather.
// 4-wide edge unroll, dual fp32 accumulator pairs for MLP.
__global__ __launch_bounds__(256) void k_agg(const unsigned* __restrict__ hw4,
        const int* __restrict__ rowptr, const int* __restrict__ colidx,
        const float* __restrict__ dinv, const float* __restrict__ bc,
        const float* __restrict__ bmean, const float* __restrict__ bvar,
        const float* __restrict__ bgamma, const float* __restrict__ bbeta,
        unsigned* __restrict__ houtb, float* __restrict__ hout32, int n){
    int node = blockIdx.x*4 + (threadIdx.x >> 6);
    int lane = threadIdx.x & 63;
    if (node >= n) return;
    unsigned self = hw4[(size_t)node*64 + lane];
    float ax = bflo(self), ay = bfhi(self);
    float bx = 0.f, by = 0.f;
    int s = rowptr[node], e = rowptr[node+1];
    int t = s;
    for (; t + 4 <= e; t += 4){
        int c0 = colidx[t],   c1 = colidx[t+1];
        int c2 = colidx[t+2], c3 = colidx[t+3];
        unsigned v0 = hw4[(size_t)c0*64 + lane];
        unsigned v1 = hw4[(size_t)c1*64 + lane];
        unsigned v2 = hw4[(size_t)c2*64 + lane];
        unsigned v3 = hw4[(size_t)c3*64 + lane];
        ax += bflo(v0); ay += bfhi(v0);
        bx += bflo(v1); by += bfhi(v1);
        ax += bflo(v2); ay += bfhi(v2);
        bx += bflo(v3); by += bfhi(v3);
    }
    for (; t < e; t++){
        unsigned v = hw4[(size_t)colidx[t]*64 + lane];
        ax += bflo(v); ay += bfhi(v);
    }
    ax += bx; ay += by;
    float dv = dinv[node];
    float2 cb  = ((const float2*)bc)[lane];
    float2 cm  = ((const float2*)bmean)[lane];
    float2 cv  = ((const float2*)bvar)[lane];
    float2 cg  = ((const float2*)bgamma)[lane];
    float2 cbe = ((const float2*)bbeta)[lane];
    float rx = (ax*dv + cb.x - cm.x) * rsqrtf(cv.x + BN_EPS) * cg.x + cbe.x;
    float ry = (ay*dv + cb.y - cm.y) * rsqrtf(cv.y + BN_EPS) * cg.y + cbe.y;
    rx = fmaxf(rx, 0.f); ry = fmaxf(ry, 0.f);
    houtb[(size_t)node*64 + lane] = packbf(rx, ry);
    if (hout32) ((float2*)hout32)[(size_t)node*64 + lane] = make_float2(rx, ry);
}

// ---------------- pooling ----------------
__global__ void k_count(const int* __restrict__ batch, int* __restrict__ gcnt, int n){
    int i = blockIdx.x*blockDim.x + threadIdx.x;
    if (i < n) atomicAdd(&gcnt[batch[i]], 1);
}

// batch sorted: run-length local reduce, flush on graph change. h >= 0 post-relu,
// so signed-int atomicMax on the bit pattern == float max, init 0.
__global__ void k_pool(const float* __restrict__ h, const int* __restrict__ batch,
        float* __restrict__ gsum, int* __restrict__ gmax, int n){
    int f = threadIdx.x;   // 128 threads = feature
    int start = blockIdx.x * POOL_TILE;
    int end = min(start + POOL_TILE, n);
    if (start >= end) return;
    int cur = batch[start];
    float s = 0.f, mx = 0.f;
    for (int i = start; i < end; i++){
        int b = batch[i];
        float v = h[(size_t)i*HD + f];
        if (b != cur){
            atomicAdd(&gsum[cur*HD+f], s);
            atomicMax(&gmax[cur*HD+f], __float_as_int(mx));
            s = 0.f; mx = 0.f; cur = b;
        }
        s += v; mx = fmaxf(mx, v);
    }
    atomicAdd(&gsum[cur*HD+f], s);
    atomicMax(&gmax[cur*HD+f], __float_as_int(mx));
}

// ---------------- head MLP ----------------
__global__ void k_mlp1(const float* __restrict__ gsum, const int* __restrict__ gmax,
        const int* __restrict__ gcnt, const float* __restrict__ W1,
        const float* __restrict__ b1, float* __restrict__ hidden){
    __shared__ float gv[2*HD];
    int g = blockIdx.x, j = threadIdx.x;
    float denom = (float)max(gcnt[g], 1);
    gv[j]    = gsum[g*HD+j] / denom;
    gv[HD+j] = __int_as_float(gmax[g*HD+j]);   // 0 for empty graphs (matches guard)
    __syncthreads();
    float acc = b1[j];
    #pragma unroll 8
    for (int k = 0; k < 2*HD; k++) acc += gv[k]*W1[k*HD + j];
    hidden[g*HD + j] = fmaxf(acc, 0.f);
}

__global__ void k_mlp2(const float* __restrict__ hidden, const float* __restrict__ W2,
        const float* __restrict__ b2, float* __restrict__ out){
    int g = blockIdx.x, c = threadIdx.x;
    if (c >= N_CLASSES) return;
    float acc = b2[c];
    #pragma unroll 4
    for (int j = 0; j < HD; j++) acc += hidden[g*HD + j]*W2[j*N_CLASSES + c];
    out[g*N_CLASSES + c] = acc;
}

// ---------------- launch ----------------
extern "C" void kernel_launch(void* const* d_in, const int* in_sizes, int n_in,
                              void* d_out, int out_size, void* d_ws, size_t ws_size,
                              hipStream_t stream){
    const float* x   = (const float*)d_in[0];
    const int*  eidx = (const int*)d_in[1];
    const int* batch = (const int*)d_in[2];
    const float* Wp  = (const float*)d_in[3];
    const float* bp  = (const float*)d_in[4];
    const float* Wc  = (const float*)d_in[5];
    const float* bc  = (const float*)d_in[6];
    const float* bng = (const float*)d_in[7];
    const float* bnb = (const float*)d_in[8];
    const float* bnm = (const float*)d_in[9];
    const float* bnv = (const float*)d_in[10];
    const float* W1  = (const float*)d_in[11];
    const float* b1  = (const float*)d_in[12];
    const float* W2  = (const float*)d_in[13];
    const float* b2  = (const float*)d_in[14];
    float* out = (float*)d_out;

    // workspace layout (~111 MB)
    char* ws = (char*)d_ws;
    size_t off = 0;
    unsigned short* h_bf  = (unsigned short*)(ws + off); off += (size_t)N_NODES*HD*2;  // 25.6 MB
    unsigned short* hw_bf = (unsigned short*)(ws + off); off += (size_t)N_NODES*HD*2;  // 25.6 MB
    float* h32    = (float*)(ws + off); off += (size_t)N_NODES*HD*4;                   // 51.2 MB
    unsigned short* WT = (unsigned short*)(ws + off); off += (size_t)N_LAYERS*HD*HD*2; // 98 KB
    float* dinv   = (float*)(ws + off); off += (size_t)N_NODES*4;
    int*   degi   = (int*)  (ws + off); off += (size_t)N_NODES*4;
    int*   rowptr = (int*)  (ws + off); off += (size_t)(N_NODES+16)*4;
    int*   cursor = (int*)  (ws + off); off += (size_t)N_NODES*4;
    int*   colidx = (int*)  (ws + off); off += (size_t)N_EDGES*4;                      // 6.4 MB
    int*   bsums  = (int*)  (ws + off); off += 512;
    float* gsum   = (float*)(ws + off); off += (size_t)N_GRAPHS*HD*4;
    int*   gmax   = (int*)  (ws + off); off += (size_t)N_GRAPHS*HD*4;
    int*   gcnt   = (int*)  (ws + off); off += 1024;
    float* hidden = (float*)(ws + off); off += (size_t)N_GRAPHS*HD*4;

    const int* rows = eidx;             // targets (aggregation index)
    const int* cols = eidx + N_EDGES;   // sources (gather index)

    hipMemsetAsync(degi, 0, (size_t)N_NODES*4, stream);
    hipMemsetAsync(gsum, 0, (size_t)(N_GRAPHS*HD*2)*4 + 1024, stream);  // gsum+gmax+gcnt

    k_degree<<<N_EDGES/256, 256, 0, stream>>>(rows, degi, N_EDGES);
    k_dinv<<<(N_NODES+255)/256, 256, 0, stream>>>(degi, dinv, N_NODES);
    int nb = (N_NODES + 1023)/1024;     // 98 <= 128
    k_scan1<<<nb, 1024, 0, stream>>>(degi, rowptr, bsums, N_NODES);
    k_scan2<<<1, 128, 0, stream>>>(bsums, nb);
    k_scan3<<<nb, 1024, 0, stream>>>(rowptr, bsums, cursor, N_NODES, N_EDGES);
    k_fill<<<N_EDGES/256, 256, 0, stream>>>(rows, cols, cursor, colidx, N_EDGES);

    k_prepW<<<(N_LAYERS*HD*HD)/256, 256, 0, stream>>>(Wc, WT);
    k_proj<<<1024, 256, 0, stream>>>(x, Wp, bp, (unsigned*)h_bf, N_NODES);

    int ntiles = (N_NODES + 127)/128;   // 782
    size_t shmem = (size_t)(2*128*LDS_PITCH)*2;   // 77,824 B -> 2 blocks/CU
    for (int l = 0; l < N_LAYERS; l++){
        k_gemm<<<ntiles, 256, shmem, stream>>>(h_bf, WT + (size_t)l*HD*HD, dinv, hw_bf, N_NODES);
        k_agg<<<(N_NODES+3)/4, 256, 0, stream>>>((const unsigned*)hw_bf, rowptr, colidx, dinv,
            bc + l*HD, bnm + l*HD, bnv + l*HD, bng + l*HD, bnb + l*HD,
            (unsigned*)h_bf, (l == N_LAYERS-1) ? h32 : nullptr, N_NODES);
    }

    k_count<<<(N_NODES+255)/256, 256, 0, stream>>>(batch, gcnt, N_NODES);
    k_pool<<<(N_NODES+POOL_TILE-1)/POOL_TILE, 128, 0, stream>>>(h32, batch, gsum, gmax, N_NODES);
    k_mlp1<<<N_GRAPHS, 128, 0, stream>>>(gsum, gmax, gcnt, W1, b1, hidden);
    k_mlp2<<<N_GRAPHS, 32, 0, stream>>>(hidden, W2, b2, out);
}

// Round 3
// 629.692 us; speedup vs baseline: 2.2182x; 1.2402x over previous
//
#include <hip/hip_runtime.h>

#define N_NODES   100000
#define N_EDGES   1600000
#define F_IN      10
#define HD        128
#define N_LAYERS  3
#define N_GRAPHS  256
#define N_CLASSES 25
#define BN_EPS    1e-5f
#define POOL_TILE 64
#define LDS_PITCH 152   // shorts; 304 B row stride: 16B-aligned, 2-way bank conflict max

typedef __attribute__((ext_vector_type(8))) short bf8;
typedef __attribute__((ext_vector_type(4))) float f32x4;

static __device__ __forceinline__ unsigned short f2bf(float f){
    unsigned u = __float_as_uint(f);
    unsigned r = (u + 0x7fffu + ((u >> 16) & 1u)) >> 16;
    return (unsigned short)r;
}
static __device__ __forceinline__ float bflo(unsigned u){ return __uint_as_float(u << 16); }
static __device__ __forceinline__ float bfhi(unsigned u){ return __uint_as_float(u & 0xffff0000u); }
static __device__ __forceinline__ unsigned packbf(float a, float b){
    return (unsigned)f2bf(a) | ((unsigned)f2bf(b) << 16);
}

// ---------------- graph build ----------------

__global__ void k_degree(const int* __restrict__ rows, int* __restrict__ degi, int e){
    int i = blockIdx.x*blockDim.x + threadIdx.x;
    if (i < e) atomicAdd(&degi[rows[i]], 1);
}

__global__ void k_dinv(const int* __restrict__ degi, float* __restrict__ dinv, int n){
    int i = blockIdx.x*blockDim.x + threadIdx.x;
    if (i < n) dinv[i] = rsqrtf((float)(degi[i] + 1));   // +1 self loop
}

__global__ void k_scan1(const int* __restrict__ cnt, int* __restrict__ excl,
                        int* __restrict__ bsums, int n){
    __shared__ int s[1024];
    int tid = threadIdx.x;
    int i = blockIdx.x*1024 + tid;
    int v = (i < n) ? cnt[i] : 0;
    s[tid] = v;
    __syncthreads();
    for (int d = 1; d < 1024; d <<= 1){
        int t = (tid >= d) ? s[tid-d] : 0;
        __syncthreads();
        s[tid] += t;
        __syncthreads();
    }
    if (i < n) excl[i] = s[tid] - v;
    if (tid == 0) bsums[blockIdx.x] = s[1023];
}

// parallel single-block exclusive scan of block sums (nb <= 128)
__global__ void k_scan2(int* bsums, int nb){
    __shared__ int s[128];
    int tid = threadIdx.x;
    int v = (tid < nb) ? bsums[tid] : 0;
    s[tid] = v;
    __syncthreads();
    for (int d = 1; d < 128; d <<= 1){
        int t = (tid >= d) ? s[tid-d] : 0;
        __syncthreads();
        s[tid] += t;
        __syncthreads();
    }
    if (tid < nb) bsums[tid] = s[tid] - v;
}

__global__ void k_scan3(int* __restrict__ rowptr, const int* __restrict__ bsums,
                        int* __restrict__ cursor, int n, int etot){
    int i = blockIdx.x*1024 + threadIdx.x;
    if (i < n){
        int v = rowptr[i] + bsums[blockIdx.x];
        rowptr[i] = v;
        cursor[i] = v;
    }
    if (i == 0) rowptr[n] = etot;
}

__global__ void k_fill(const int* __restrict__ rows, const int* __restrict__ cols,
                       int* __restrict__ cursor, int* __restrict__ colidx, int e){
    int i = blockIdx.x*blockDim.x + threadIdx.x;
    if (i < e){
        int r = rows[i];
        int pos = atomicAdd(&cursor[r], 1);
        colidx[pos] = cols[i];
    }
}

// ---------------- weight transpose+cast: WT[l][n][k] bf16 ----------------
__global__ void k_prepW(const float* __restrict__ Wc, unsigned short* __restrict__ WT){
    int i = blockIdx.x*256 + threadIdx.x;      // over L*128*128
    int l = i >> 14;
    int r = (i >> 7) & 127;                    // k
    int c = i & 127;                           // n
    WT[(l << 14) + c*HD + r] = f2bf(Wc[i]);
}

// ---------------- input projection: h = relu(x @ Wp + bp), bf16 out ----------------
__global__ void k_proj(const float* __restrict__ x, const float* __restrict__ Wp,
                       const float* __restrict__ bp, unsigned* __restrict__ hbf, int n){
    __shared__ float sW[F_IN*HD];
    __shared__ float sb[HD];
    for (int t = threadIdx.x; t < F_IN*HD; t += 256) sW[t] = Wp[t];
    if (threadIdx.x < HD) sb[threadIdx.x] = bp[threadIdx.x];
    __syncthreads();
    int j  = threadIdx.x & 63;      // feature pair
    int ln = threadIdx.x >> 6;      // 4 nodes per block-iter
    for (int n0 = blockIdx.x*4 + ln; n0 < n; n0 += gridDim.x*4){
        float a0 = sb[2*j], a1 = sb[2*j+1];
        #pragma unroll
        for (int k = 0; k < F_IN; k++){
            float xv = x[(size_t)n0*F_IN + k];
            a0 += xv * sW[k*HD + 2*j];
            a1 += xv * sW[k*HD + 2*j+1];
        }
        hbf[(size_t)n0*64 + j] = packbf(fmaxf(a0, 0.f), fmaxf(a1, 0.f));
    }
}

// ---------------- layer GEMM (bf16 MFMA): hw = bf16((h @ Wc) * dinv[row]) ----------------
// 128-row tile per block; K=128 and B^T fully LDS-resident. Wave = 32 rows x 128 cols
// = 2x8 tiles of 16x16x32 MFMA, 64 f32 acc regs.
__global__ __launch_bounds__(256) void k_gemm(const unsigned short* __restrict__ hbf,
        const unsigned short* __restrict__ WT, const float* __restrict__ dinv,
        unsigned short* __restrict__ hw, int n){
    extern __shared__ char smem[];
    unsigned short* As = (unsigned short*)smem;            // 128 x LDS_PITCH
    unsigned short* Bs = As + 128*LDS_PITCH;               // 128 x LDS_PITCH
    int tid = threadIdx.x;
    int row0 = blockIdx.x * 128;

    const uint4* h4 = (const uint4*)hbf;
    const uint4* w4 = (const uint4*)WT;
    #pragma unroll
    for (int q = tid; q < 2048; q += 256){                 // 128 rows x 16 chunks of 16B
        int r = q >> 4, c = q & 15;
        uint4 v = make_uint4(0u,0u,0u,0u);
        if (row0 + r < n) v = h4[(size_t)(row0 + r)*16 + c];
        *(uint4*)&As[r*LDS_PITCH + c*8] = v;
        *(uint4*)&Bs[r*LDS_PITCH + c*8] = w4[r*16 + c];
    }
    __syncthreads();

    int w = tid >> 6, lane = tid & 63;
    int l15 = lane & 15, quad = lane >> 4;
    f32x4 acc[2][8];
    #pragma unroll
    for (int rt = 0; rt < 2; rt++)
        #pragma unroll
        for (int ct = 0; ct < 8; ct++) acc[rt][ct] = (f32x4){0.f,0.f,0.f,0.f};

    int arow = w*32 + l15;
    #pragma unroll
    for (int kc = 0; kc < 4; kc++){
        int ko = kc*32 + quad*8;
        bf8 a0 = *(const bf8*)&As[arow*LDS_PITCH + ko];
        bf8 a1 = *(const bf8*)&As[(arow+16)*LDS_PITCH + ko];
        #pragma unroll
        for (int ct = 0; ct < 8; ct++){
            bf8 b = *(const bf8*)&Bs[(ct*16 + l15)*LDS_PITCH + ko];
            acc[0][ct] = __builtin_amdgcn_mfma_f32_16x16x32_bf16(a0, b, acc[0][ct], 0, 0, 0);
            acc[1][ct] = __builtin_amdgcn_mfma_f32_16x16x32_bf16(a1, b, acc[1][ct], 0, 0, 0);
        }
    }

    #pragma unroll
    for (int rt = 0; rt < 2; rt++){
        #pragma unroll
        for (int reg = 0; reg < 4; reg++){
            int row = row0 + w*32 + rt*16 + quad*4 + reg;
            if (row < n){
                float dv = dinv[row];
                #pragma unroll
                for (int ct = 0; ct < 8; ct++){
                    hw[(size_t)row*HD + ct*16 + l15] = f2bf(acc[rt][ct][reg] * dv);
                }
            }
        }
    }
}

// ---------------- aggregation + bias + BN + relu ----------------
// one wave per node; lane holds bf16x2 (4 B) -> 256 B coalesced row gather.
__global__ __launch_bounds__(256) void k_agg(const unsigned* __restrict__ hw4,
        const int* __restrict__ rowptr, const int* __restrict__ colidx,
        const float* __restrict__ dinv, const float* __restrict__ bc,
        const float* __restrict__ bmean, const float* __restrict__ bvar,
        const float* __restrict__ bgamma, const float* __restrict__ bbeta,
        unsigned* __restrict__ houtb, float* __restrict__ hout32, int n){
    int node = blockIdx.x*4 + (threadIdx.x >> 6);
    int lane = threadIdx.x & 63;
    if (node >= n) return;
    unsigned self = hw4[(size_t)node*64 + lane];
    float ax = bflo(self), ay = bfhi(self);
    float bx = 0.f, by = 0.f;
    int s = rowptr[node], e = rowptr[node+1];
    int t = s;
    for (; t + 4 <= e; t += 4){
        int c0 = colidx[t],   c1 = colidx[t+1];
        int c2 = colidx[t+2], c3 = colidx[t+3];
        unsigned v0 = hw4[(size_t)c0*64 + lane];
        unsigned v1 = hw4[(size_t)c1*64 + lane];
        unsigned v2 = hw4[(size_t)c2*64 + lane];
        unsigned v3 = hw4[(size_t)c3*64 + lane];
        ax += bflo(v0); ay += bfhi(v0);
        bx += bflo(v1); by += bfhi(v1);
        ax += bflo(v2); ay += bfhi(v2);
        bx += bflo(v3); by += bfhi(v3);
    }
    for (; t < e; t++){
        unsigned v = hw4[(size_t)colidx[t]*64 + lane];
        ax += bflo(v); ay += bfhi(v);
    }
    ax += bx; ay += by;
    float dv = dinv[node];
    float2 cb  = ((const float2*)bc)[lane];
    float2 cm  = ((const float2*)bmean)[lane];
    float2 cv  = ((const float2*)bvar)[lane];
    float2 cg  = ((const float2*)bgamma)[lane];
    float2 cbe = ((const float2*)bbeta)[lane];
    float rx = (ax*dv + cb.x - cm.x) * rsqrtf(cv.x + BN_EPS) * cg.x + cbe.x;
    float ry = (ay*dv + cb.y - cm.y) * rsqrtf(cv.y + BN_EPS) * cg.y + cbe.y;
    rx = fmaxf(rx, 0.f); ry = fmaxf(ry, 0.f);
    houtb[(size_t)node*64 + lane] = packbf(rx, ry);
    if (hout32) ((float2*)hout32)[(size_t)node*64 + lane] = make_float2(rx, ry);
}

// ---------------- graph-size count via binary search (batch is sorted) ----------------
// replaces the atomic histogram: 100k same-address device atomics serialized
// at ~157 us (R2 counters: VALUBusy 0.01%, 21 GB/s). Exact integer result.
__global__ void k_count(const int* __restrict__ batch, int* __restrict__ gcnt, int n){
    int g = threadIdx.x;           // one thread per graph, single block
    int lo = 0, hi = n;
    while (lo < hi){ int mid = (lo + hi) >> 1; if (batch[mid] < g) lo = mid + 1; else hi = mid; }
    int start = lo;
    hi = n;
    while (lo < hi){ int mid = (lo + hi) >> 1; if (batch[mid] < g + 1) lo = mid + 1; else hi = mid; }
    gcnt[g] = lo - start;
}

// batch sorted: run-length local reduce, flush on graph change. h >= 0 post-relu,
// so signed-int atomicMax on the bit pattern == float max, init 0.
__global__ void k_pool(const float* __restrict__ h, const int* __restrict__ batch,
        float* __restrict__ gsum, int* __restrict__ gmax, int n){
    int f = threadIdx.x;   // 128 threads = feature
    int start = blockIdx.x * POOL_TILE;
    int end = min(start + POOL_TILE, n);
    if (start >= end) return;
    int cur = batch[start];
    float s = 0.f, mx = 0.f;
    for (int i = start; i < end; i++){
        int b = batch[i];
        float v = h[(size_t)i*HD + f];
        if (b != cur){
            atomicAdd(&gsum[cur*HD+f], s);
            atomicMax(&gmax[cur*HD+f], __float_as_int(mx));
            s = 0.f; mx = 0.f; cur = b;
        }
        s += v; mx = fmaxf(mx, v);
    }
    atomicAdd(&gsum[cur*HD+f], s);
    atomicMax(&gmax[cur*HD+f], __float_as_int(mx));
}

// ---------------- head MLP ----------------
__global__ void k_mlp1(const float* __restrict__ gsum, const int* __restrict__ gmax,
        const int* __restrict__ gcnt, const float* __restrict__ W1,
        const float* __restrict__ b1, float* __restrict__ hidden){
    __shared__ float gv[2*HD];
    int g = blockIdx.x, j = threadIdx.x;
    float denom = (float)max(gcnt[g], 1);
    gv[j]    = gsum[g*HD+j] / denom;
    gv[HD+j] = __int_as_float(gmax[g*HD+j]);   // 0 for empty graphs (matches guard)
    __syncthreads();
    float acc = b1[j];
    #pragma unroll 8
    for (int k = 0; k < 2*HD; k++) acc += gv[k]*W1[k*HD + j];
    hidden[g*HD + j] = fmaxf(acc, 0.f);
}

__global__ void k_mlp2(const float* __restrict__ hidden, const float* __restrict__ W2,
        const float* __restrict__ b2, float* __restrict__ out){
    int g = blockIdx.x, c = threadIdx.x;
    if (c >= N_CLASSES) return;
    float acc = b2[c];
    #pragma unroll 4
    for (int j = 0; j < HD; j++) acc += hidden[g*HD + j]*W2[j*N_CLASSES + c];
    out[g*N_CLASSES + c] = acc;
}

// ---------------- launch ----------------
extern "C" void kernel_launch(void* const* d_in, const int* in_sizes, int n_in,
                              void* d_out, int out_size, void* d_ws, size_t ws_size,
                              hipStream_t stream){
    const float* x   = (const float*)d_in[0];
    const int*  eidx = (const int*)d_in[1];
    const int* batch = (const int*)d_in[2];
    const float* Wp  = (const float*)d_in[3];
    const float* bp  = (const float*)d_in[4];
    const float* Wc  = (const float*)d_in[5];
    const float* bc  = (const float*)d_in[6];
    const float* bng = (const float*)d_in[7];
    const float* bnb = (const float*)d_in[8];
    const float* bnm = (const float*)d_in[9];
    const float* bnv = (const float*)d_in[10];
    const float* W1  = (const float*)d_in[11];
    const float* b1  = (const float*)d_in[12];
    const float* W2  = (const float*)d_in[13];
    const float* b2  = (const float*)d_in[14];
    float* out = (float*)d_out;

    // workspace layout (~111 MB)
    char* ws = (char*)d_ws;
    size_t off = 0;
    unsigned short* h_bf  = (unsigned short*)(ws + off); off += (size_t)N_NODES*HD*2;  // 25.6 MB
    unsigned short* hw_bf = (unsigned short*)(ws + off); off += (size_t)N_NODES*HD*2;  // 25.6 MB
    float* h32    = (float*)(ws + off); off += (size_t)N_NODES*HD*4;                   // 51.2 MB
    unsigned short* WT = (unsigned short*)(ws + off); off += (size_t)N_LAYERS*HD*HD*2; // 98 KB
    float* dinv   = (float*)(ws + off); off += (size_t)N_NODES*4;
    int*   degi   = (int*)  (ws + off); off += (size_t)N_NODES*4;
    int*   rowptr = (int*)  (ws + off); off += (size_t)(N_NODES+16)*4;
    int*   cursor = (int*)  (ws + off); off += (size_t)N_NODES*4;
    int*   colidx = (int*)  (ws + off); off += (size_t)N_EDGES*4;                      // 6.4 MB
    int*   bsums  = (int*)  (ws + off); off += 512;
    float* gsum   = (float*)(ws + off); off += (size_t)N_GRAPHS*HD*4;
    int*   gmax   = (int*)  (ws + off); off += (size_t)N_GRAPHS*HD*4;
    int*   gcnt   = (int*)  (ws + off); off += 1024;
    float* hidden = (float*)(ws + off); off += (size_t)N_GRAPHS*HD*4;

    const int* rows = eidx;             // targets (aggregation index)
    const int* cols = eidx + N_EDGES;   // sources (gather index)

    hipMemsetAsync(degi, 0, (size_t)N_NODES*4, stream);
    hipMemsetAsync(gsum, 0, (size_t)(N_GRAPHS*HD*2)*4, stream);  // gsum+gmax

    k_degree<<<N_EDGES/256, 256, 0, stream>>>(rows, degi, N_EDGES);
    k_dinv<<<(N_NODES+255)/256, 256, 0, stream>>>(degi, dinv, N_NODES);
    int nb = (N_NODES + 1023)/1024;     // 98 <= 128
    k_scan1<<<nb, 1024, 0, stream>>>(degi, rowptr, bsums, N_NODES);
    k_scan2<<<1, 128, 0, stream>>>(bsums, nb);
    k_scan3<<<nb, 1024, 0, stream>>>(rowptr, bsums, cursor, N_NODES, N_EDGES);
    k_fill<<<N_EDGES/256, 256, 0, stream>>>(rows, cols, cursor, colidx, N_EDGES);

    k_prepW<<<(N_LAYERS*HD*HD)/256, 256, 0, stream>>>(Wc, WT);
    k_proj<<<1024, 256, 0, stream>>>(x, Wp, bp, (unsigned*)h_bf, N_NODES);

    int ntiles = (N_NODES + 127)/128;   // 782
    size_t shmem = (size_t)(2*128*LDS_PITCH)*2;   // 77,824 B -> 2 blocks/CU
    for (int l = 0; l < N_LAYERS; l++){
        k_gemm<<<ntiles, 256, shmem, stream>>>(h_bf, WT + (size_t)l*HD*HD, dinv, hw_bf, N_NODES);
        k_agg<<<(N_NODES+3)/4, 256, 0, stream>>>((const unsigned*)hw_bf, rowptr, colidx, dinv,
            bc + l*HD, bnm + l*HD, bnv + l*HD, bng + l*HD, bnb + l*HD,
            (unsigned*)h_bf, (l == N_LAYERS-1) ? h32 : nullptr, N_NODES);
    }

    k_count<<<1, 256, 0, stream>>>(batch, gcnt, N_NODES);
    k_pool<<<(N_NODES+POOL_TILE-1)/POOL_TILE, 128, 0, stream>>>(h32, batch, gsum, gmax, N_NODES);
    k_mlp1<<<N_GRAPHS, 128, 0, stream>>>(gsum, gmax, gcnt, W1, b1, hidden);
    k_mlp2<<<N_GRAPHS, 32, 0, stream>>>(hidden, W2, b2, out);
}

// Round 4
// 479.172 us; speedup vs baseline: 2.9150x; 1.3141x over previous
//
#include <hip/hip_runtime.h>

#define N_NODES   100000
#define N_EDGES   1600000
#define F_IN      10
#define HD        128
#define N_LAYERS  3
#define N_GRAPHS  256
#define N_CLASSES 25
#define BN_EPS    1e-5f
#define POOL_TILE 64
#define LDS_PITCH 152   // shorts; 304 B row stride: 16B-aligned, 2-way bank conflict max

#define NBUCK     196   // ceil(100000/512) row buckets (row >> 9)
#define SCAT_TILE 4096  // edges per k_scatter/k_hist block
#define BUCK_CAP  16384 // LDS stage cap per bucket (mean 8192, sd ~90 -> 45 sigma headroom)

typedef __attribute__((ext_vector_type(8))) short bf8;
typedef __attribute__((ext_vector_type(4))) float f32x4;

static __device__ __forceinline__ unsigned short f2bf(float f){
    unsigned u = __float_as_uint(f);
    unsigned r = (u + 0x7fffu + ((u >> 16) & 1u)) >> 16;
    return (unsigned short)r;
}
static __device__ __forceinline__ float bflo(unsigned u){ return __uint_as_float(u << 16); }
static __device__ __forceinline__ float bfhi(unsigned u){ return __uint_as_float(u & 0xffff0000u); }
static __device__ __forceinline__ unsigned packbf(float a, float b){
    return (unsigned)f2bf(a) | ((unsigned)f2bf(b) << 16);
}

// ---------------- graph build: bucketed counting sort ----------------
// R3 k_fill burned 123 us on 1.6M random 4B atomic/scatter stores (105 MB of
// line-granule writeback). Counting sort stages everything in LDS and makes
// every global write a coalesced stream.

// pass 1: bucket histogram (bucket = row >> 9)
__global__ __launch_bounds__(256) void k_hist(const int* __restrict__ rows,
        int* __restrict__ gcount, int e){
    __shared__ int lhist[NBUCK];
    int t = threadIdx.x;
    if (t < NBUCK) lhist[t] = 0;
    __syncthreads();
    int i0 = blockIdx.x*SCAT_TILE + t;
    #pragma unroll
    for (int k = 0; k < 16; k++){
        int i = i0 + k*256;
        if (i < e) atomicAdd(&lhist[rows[i] >> 9], 1);
    }
    __syncthreads();
    if (t < NBUCK && lhist[t] > 0) atomicAdd(&gcount[t], lhist[t]);
}

// pass 2: scan bucket totals -> base/cursor; also rowptr[n] = e
__global__ void k_scanb(const int* __restrict__ gcount, int* __restrict__ base,
        int* __restrict__ cursor, int* __restrict__ rowptr, int e, int n){
    __shared__ int s[256];
    int t = threadIdx.x;
    int v = (t < NBUCK) ? gcount[t] : 0;
    s[t] = v;
    __syncthreads();
    for (int d = 1; d < 256; d <<= 1){
        int tv = (t >= d) ? s[t-d] : 0;
        __syncthreads();
        s[t] += tv;
        __syncthreads();
    }
    if (t < NBUCK){ base[t] = s[t] - v; cursor[t] = s[t] - v; }
    if (t == 0){ base[NBUCK] = e; rowptr[n] = e; }
}

// pass 3: block-local counting sort by bucket, then bucket-ordered global write.
// ebuf element packs (localrow << 17) | col  (col < 2^17, localrow < 512).
__global__ __launch_bounds__(256) void k_scatter(const int* __restrict__ rows,
        const int* __restrict__ cols, int* __restrict__ cursor,
        unsigned* __restrict__ ebuf, int e){
    __shared__ int lbase[NBUCK];
    __shared__ int lcur[NBUCK];
    __shared__ int gbase[NBUCK];
    __shared__ int sbuf[256];
    __shared__ unsigned sedge[SCAT_TILE];
    __shared__ unsigned char sbuck[SCAT_TILE];
    int t = threadIdx.x;
    int i0 = blockIdx.x*SCAT_TILE + t;
    int r[16], c[16];
    if (t < NBUCK) lcur[t] = 0;
    __syncthreads();
    #pragma unroll
    for (int k = 0; k < 16; k++){
        int i = i0 + k*256;
        if (i < e){
            r[k] = rows[i]; c[k] = cols[i];
            atomicAdd(&lcur[r[k] >> 9], 1);
        } else r[k] = -1;
    }
    __syncthreads();
    int myc = (t < NBUCK) ? lcur[t] : 0;
    sbuf[t] = myc;
    __syncthreads();
    for (int d = 1; d < 256; d <<= 1){
        int tv = (t >= d) ? sbuf[t-d] : 0;
        __syncthreads();
        sbuf[t] += tv;
        __syncthreads();
    }
    if (t < NBUCK){
        lbase[t] = sbuf[t] - myc;
        lcur[t]  = sbuf[t] - myc;
        if (myc > 0) gbase[t] = atomicAdd(&cursor[t], myc);
    }
    __syncthreads();
    #pragma unroll
    for (int k = 0; k < 16; k++){
        if (r[k] >= 0){
            int bk = r[k] >> 9;
            int off = atomicAdd(&lcur[bk], 1);
            sedge[off] = ((unsigned)(r[k] & 511) << 17) | (unsigned)c[k];
            sbuck[off] = (unsigned char)bk;
        }
    }
    __syncthreads();
    int tot = sbuf[255];
    for (int i = t; i < tot; i += 256){
        int bk = sbuck[i];
        ebuf[gbase[bk] + (i - lbase[bk])] = sedge[i];
    }
}

// pass 4: one block per bucket -> rowptr, dinv, coalesced colidx.
__global__ __launch_bounds__(512) void k_build(const unsigned* __restrict__ ebuf,
        const int* __restrict__ base, int* __restrict__ rowptr,
        float* __restrict__ dinv, int* __restrict__ colidx, int n){
    __shared__ int hist[512];
    __shared__ int cur[512];
    __shared__ int colstage[BUCK_CAP];
    int b = blockIdx.x;
    int s = base[b], e = base[b+1];
    int cnt = e - s;
    int row0 = b << 9;
    int nrows = min(512, n - row0);
    int t = threadIdx.x;
    hist[t] = 0;
    __syncthreads();
    for (int i = t; i < cnt; i += 512)
        atomicAdd(&hist[ebuf[s + i] >> 17], 1);
    __syncthreads();
    int myc = hist[t];
    cur[t] = myc;
    __syncthreads();
    for (int d = 1; d < 512; d <<= 1){
        int tv = (t >= d) ? cur[t-d] : 0;
        __syncthreads();
        cur[t] += tv;
        __syncthreads();
    }
    int excl = cur[t] - myc;
    if (t < nrows){
        rowptr[row0 + t] = s + excl;
        dinv[row0 + t] = rsqrtf((float)(myc + 1));   // +1 self loop
    }
    cur[t] = excl;
    __syncthreads();
    for (int i = t; i < cnt; i += 512){
        unsigned v = ebuf[s + i];
        int off = atomicAdd(&cur[v >> 17], 1);
        colstage[off] = (int)(v & 0x1ffffu);
    }
    __syncthreads();
    for (int i = t; i < cnt; i += 512)
        colidx[s + i] = colstage[i];
}

// ---------------- weight transpose+cast: WT[l][n][k] bf16 ----------------
__global__ void k_prepW(const float* __restrict__ Wc, unsigned short* __restrict__ WT){
    int i = blockIdx.x*256 + threadIdx.x;      // over L*128*128
    int l = i >> 14;
    int r = (i >> 7) & 127;                    // k
    int c = i & 127;                           // n
    WT[(l << 14) + c*HD + r] = f2bf(Wc[i]);
}

// ---------------- input projection: h = relu(x @ Wp + bp), bf16 out ----------------
__global__ void k_proj(const float* __restrict__ x, const float* __restrict__ Wp,
                       const float* __restrict__ bp, unsigned* __restrict__ hbf, int n){
    __shared__ float sW[F_IN*HD];
    __shared__ float sb[HD];
    for (int t = threadIdx.x; t < F_IN*HD; t += 256) sW[t] = Wp[t];
    if (threadIdx.x < HD) sb[threadIdx.x] = bp[threadIdx.x];
    __syncthreads();
    int j  = threadIdx.x & 63;      // feature pair
    int ln = threadIdx.x >> 6;      // 4 nodes per block-iter
    for (int n0 = blockIdx.x*4 + ln; n0 < n; n0 += gridDim.x*4){
        float a0 = sb[2*j], a1 = sb[2*j+1];
        #pragma unroll
        for (int k = 0; k < F_IN; k++){
            float xv = x[(size_t)n0*F_IN + k];
            a0 += xv * sW[k*HD + 2*j];
            a1 += xv * sW[k*HD + 2*j+1];
        }
        hbf[(size_t)n0*64 + j] = packbf(fmaxf(a0, 0.f), fmaxf(a1, 0.f));
    }
}

// ---------------- layer GEMM (bf16 MFMA): hw = bf16((h @ Wc) * dinv[row]) ----------------
__global__ __launch_bounds__(256) void k_gemm(const unsigned short* __restrict__ hbf,
        const unsigned short* __restrict__ WT, const float* __restrict__ dinv,
        unsigned short* __restrict__ hw, int n){
    extern __shared__ char smem[];
    unsigned short* As = (unsigned short*)smem;            // 128 x LDS_PITCH
    unsigned short* Bs = As + 128*LDS_PITCH;               // 128 x LDS_PITCH
    int tid = threadIdx.x;
    int row0 = blockIdx.x * 128;

    const uint4* h4 = (const uint4*)hbf;
    const uint4* w4 = (const uint4*)WT;
    #pragma unroll
    for (int q = tid; q < 2048; q += 256){                 // 128 rows x 16 chunks of 16B
        int r = q >> 4, c = q & 15;
        uint4 v = make_uint4(0u,0u,0u,0u);
        if (row0 + r < n) v = h4[(size_t)(row0 + r)*16 + c];
        *(uint4*)&As[r*LDS_PITCH + c*8] = v;
        *(uint4*)&Bs[r*LDS_PITCH + c*8] = w4[r*16 + c];
    }
    __syncthreads();

    int w = tid >> 6, lane = tid & 63;
    int l15 = lane & 15, quad = lane >> 4;
    f32x4 acc[2][8];
    #pragma unroll
    for (int rt = 0; rt < 2; rt++)
        #pragma unroll
        for (int ct = 0; ct < 8; ct++) acc[rt][ct] = (f32x4){0.f,0.f,0.f,0.f};

    int arow = w*32 + l15;
    #pragma unroll
    for (int kc = 0; kc < 4; kc++){
        int ko = kc*32 + quad*8;
        bf8 a0 = *(const bf8*)&As[arow*LDS_PITCH + ko];
        bf8 a1 = *(const bf8*)&As[(arow+16)*LDS_PITCH + ko];
        #pragma unroll
        for (int ct = 0; ct < 8; ct++){
            bf8 b = *(const bf8*)&Bs[(ct*16 + l15)*LDS_PITCH + ko];
            acc[0][ct] = __builtin_amdgcn_mfma_f32_16x16x32_bf16(a0, b, acc[0][ct], 0, 0, 0);
            acc[1][ct] = __builtin_amdgcn_mfma_f32_16x16x32_bf16(a1, b, acc[1][ct], 0, 0, 0);
        }
    }

    #pragma unroll
    for (int rt = 0; rt < 2; rt++){
        #pragma unroll
        for (int reg = 0; reg < 4; reg++){
            int row = row0 + w*32 + rt*16 + quad*4 + reg;
            if (row < n){
                float dv = dinv[row];
                #pragma unroll
                for (int ct = 0; ct < 8; ct++){
                    hw[(size_t)row*HD + ct*16 + l15] = f2bf(acc[rt][ct][reg] * dv);
                }
            }
        }
    }
}

// ---------------- aggregation + bias + BN + relu ----------------
__global__ __launch_bounds__(256) void k_agg(const unsigned* __restrict__ hw4,
        const int* __restrict__ rowptr, const int* __restrict__ colidx,
        const float* __restrict__ dinv, const float* __restrict__ bc,
        const float* __restrict__ bmean, const float* __restrict__ bvar,
        const float* __restrict__ bgamma, const float* __restrict__ bbeta,
        unsigned* __restrict__ houtb, float* __restrict__ hout32, int n){
    int node = blockIdx.x*4 + (threadIdx.x >> 6);
    int lane = threadIdx.x & 63;
    if (node >= n) return;
    unsigned self = hw4[(size_t)node*64 + lane];
    float ax = bflo(self), ay = bfhi(self);
    float bx = 0.f, by = 0.f;
    int s = rowptr[node], e = rowptr[node+1];
    int t = s;
    for (; t + 4 <= e; t += 4){
        int c0 = colidx[t],   c1 = colidx[t+1];
        int c2 = colidx[t+2], c3 = colidx[t+3];
        unsigned v0 = hw4[(size_t)c0*64 + lane];
        unsigned v1 = hw4[(size_t)c1*64 + lane];
        unsigned v2 = hw4[(size_t)c2*64 + lane];
        unsigned v3 = hw4[(size_t)c3*64 + lane];
        ax += bflo(v0); ay += bfhi(v0);
        bx += bflo(v1); by += bfhi(v1);
        ax += bflo(v2); ay += bfhi(v2);
        bx += bflo(v3); by += bfhi(v3);
    }
    for (; t < e; t++){
        unsigned v = hw4[(size_t)colidx[t]*64 + lane];
        ax += bflo(v); ay += bfhi(v);
    }
    ax += bx; ay += by;
    float dv = dinv[node];
    float2 cb  = ((const float2*)bc)[lane];
    float2 cm  = ((const float2*)bmean)[lane];
    float2 cv  = ((const float2*)bvar)[lane];
    float2 cg  = ((const float2*)bgamma)[lane];
    float2 cbe = ((const float2*)bbeta)[lane];
    float rx = (ax*dv + cb.x - cm.x) * rsqrtf(cv.x + BN_EPS) * cg.x + cbe.x;
    float ry = (ay*dv + cb.y - cm.y) * rsqrtf(cv.y + BN_EPS) * cg.y + cbe.y;
    rx = fmaxf(rx, 0.f); ry = fmaxf(ry, 0.f);
    houtb[(size_t)node*64 + lane] = packbf(rx, ry);
    if (hout32) ((float2*)hout32)[(size_t)node*64 + lane] = make_float2(rx, ry);
}

// ---------------- graph-size count via binary search (batch sorted) ----------------
__global__ void k_count(const int* __restrict__ batch, int* __restrict__ gcnt, int n){
    int g = threadIdx.x;           // one thread per graph, single block
    int lo = 0, hi = n;
    while (lo < hi){ int mid = (lo + hi) >> 1; if (batch[mid] < g) lo = mid + 1; else hi = mid; }
    int start = lo;
    hi = n;
    while (lo < hi){ int mid = (lo + hi) >> 1; if (batch[mid] < g + 1) lo = mid + 1; else hi = mid; }
    gcnt[g] = lo - start;
}

// batch sorted: run-length local reduce, flush on graph change. h >= 0 post-relu,
// so signed-int atomicMax on the bit pattern == float max, init 0.
__global__ void k_pool(const float* __restrict__ h, const int* __restrict__ batch,
        float* __restrict__ gsum, int* __restrict__ gmax, int n){
    int f = threadIdx.x;   // 128 threads = feature
    int start = blockIdx.x * POOL_TILE;
    int end = min(start + POOL_TILE, n);
    if (start >= end) return;
    int cur = batch[start];
    float s = 0.f, mx = 0.f;
    for (int i = start; i < end; i++){
        int b = batch[i];
        float v = h[(size_t)i*HD + f];
        if (b != cur){
            atomicAdd(&gsum[cur*HD+f], s);
            atomicMax(&gmax[cur*HD+f], __float_as_int(mx));
            s = 0.f; mx = 0.f; cur = b;
        }
        s += v; mx = fmaxf(mx, v);
    }
    atomicAdd(&gsum[cur*HD+f], s);
    atomicMax(&gmax[cur*HD+f], __float_as_int(mx));
}

// ---------------- head MLP ----------------
__global__ void k_mlp1(const float* __restrict__ gsum, const int* __restrict__ gmax,
        const int* __restrict__ gcnt, const float* __restrict__ W1,
        const float* __restrict__ b1, float* __restrict__ hidden){
    __shared__ float gv[2*HD];
    int g = blockIdx.x, j = threadIdx.x;
    float denom = (float)max(gcnt[g], 1);
    gv[j]    = gsum[g*HD+j] / denom;
    gv[HD+j] = __int_as_float(gmax[g*HD+j]);   // 0 for empty graphs (matches guard)
    __syncthreads();
    float acc = b1[j];
    #pragma unroll 8
    for (int k = 0; k < 2*HD; k++) acc += gv[k]*W1[k*HD + j];
    hidden[g*HD + j] = fmaxf(acc, 0.f);
}

__global__ void k_mlp2(const float* __restrict__ hidden, const float* __restrict__ W2,
        const float* __restrict__ b2, float* __restrict__ out){
    int g = blockIdx.x, c = threadIdx.x;
    if (c >= N_CLASSES) return;
    float acc = b2[c];
    #pragma unroll 4
    for (int j = 0; j < HD; j++) acc += hidden[g*HD + j]*W2[j*N_CLASSES + c];
    out[g*N_CLASSES + c] = acc;
}

// ---------------- launch ----------------
extern "C" void kernel_launch(void* const* d_in, const int* in_sizes, int n_in,
                              void* d_out, int out_size, void* d_ws, size_t ws_size,
                              hipStream_t stream){
    const float* x   = (const float*)d_in[0];
    const int*  eidx = (const int*)d_in[1];
    const int* batch = (const int*)d_in[2];
    const float* Wp  = (const float*)d_in[3];
    const float* bp  = (const float*)d_in[4];
    const float* Wc  = (const float*)d_in[5];
    const float* bc  = (const float*)d_in[6];
    const float* bng = (const float*)d_in[7];
    const float* bnb = (const float*)d_in[8];
    const float* bnm = (const float*)d_in[9];
    const float* bnv = (const float*)d_in[10];
    const float* W1  = (const float*)d_in[11];
    const float* b1  = (const float*)d_in[12];
    const float* W2  = (const float*)d_in[13];
    const float* b2  = (const float*)d_in[14];
    float* out = (float*)d_out;

    // workspace layout (~118 MB)
    char* ws = (char*)d_ws;
    size_t off = 0;
    unsigned short* h_bf  = (unsigned short*)(ws + off); off += (size_t)N_NODES*HD*2;  // 25.6 MB
    unsigned short* hw_bf = (unsigned short*)(ws + off); off += (size_t)N_NODES*HD*2;  // 25.6 MB
    float* h32    = (float*)(ws + off); off += (size_t)N_NODES*HD*4;                   // 51.2 MB
    unsigned short* WT = (unsigned short*)(ws + off); off += (size_t)N_LAYERS*HD*HD*2; // 98 KB
    float* dinv   = (float*)(ws + off); off += (size_t)N_NODES*4;
    int*   rowptr = (int*)  (ws + off); off += (size_t)(N_NODES+16)*4;
    int*   colidx = (int*)  (ws + off); off += (size_t)N_EDGES*4;                      // 6.4 MB
    unsigned* ebuf= (unsigned*)(ws + off); off += (size_t)N_EDGES*4;                   // 6.4 MB
    int*   gcount = (int*)  (ws + off); off += 1024;
    int*   bbase  = (int*)  (ws + off); off += 1024;
    int*   bcur   = (int*)  (ws + off); off += 1024;
    float* gsum   = (float*)(ws + off); off += (size_t)N_GRAPHS*HD*4;
    int*   gmax   = (int*)  (ws + off); off += (size_t)N_GRAPHS*HD*4;
    int*   gcnt   = (int*)  (ws + off); off += 1024;
    float* hidden = (float*)(ws + off); off += (size_t)N_GRAPHS*HD*4;

    const int* rows = eidx;             // targets (aggregation index)
    const int* cols = eidx + N_EDGES;   // sources (gather index)

    hipMemsetAsync(gcount, 0, 1024, stream);
    hipMemsetAsync(gsum, 0, (size_t)(N_GRAPHS*HD*2)*4, stream);  // gsum+gmax

    int nsb = (N_EDGES + SCAT_TILE - 1)/SCAT_TILE;   // 391
    k_hist   <<<nsb, 256, 0, stream>>>(rows, gcount, N_EDGES);
    k_scanb  <<<1, 256, 0, stream>>>(gcount, bbase, bcur, rowptr, N_EDGES, N_NODES);
    k_scatter<<<nsb, 256, 0, stream>>>(rows, cols, bcur, ebuf, N_EDGES);
    k_build  <<<NBUCK, 512, 0, stream>>>(ebuf, bbase, rowptr, dinv, colidx, N_NODES);

    k_prepW<<<(N_LAYERS*HD*HD)/256, 256, 0, stream>>>(Wc, WT);
    k_proj<<<1024, 256, 0, stream>>>(x, Wp, bp, (unsigned*)h_bf, N_NODES);

    int ntiles = (N_NODES + 127)/128;   // 782
    size_t shmem = (size_t)(2*128*LDS_PITCH)*2;   // 77,824 B -> 2 blocks/CU
    for (int l = 0; l < N_LAYERS; l++){
        k_gemm<<<ntiles, 256, shmem, stream>>>(h_bf, WT + (size_t)l*HD*HD, dinv, hw_bf, N_NODES);
        k_agg<<<(N_NODES+3)/4, 256, 0, stream>>>((const unsigned*)hw_bf, rowptr, colidx, dinv,
            bc + l*HD, bnm + l*HD, bnv + l*HD, bng + l*HD, bnb + l*HD,
            (unsigned*)h_bf, (l == N_LAYERS-1) ? h32 : nullptr, N_NODES);
    }

    k_count<<<1, 256, 0, stream>>>(batch, gcnt, N_NODES);
    k_pool<<<(N_NODES+POOL_TILE-1)/POOL_TILE, 128, 0, stream>>>(h32, batch, gsum, gmax, N_NODES);
    k_mlp1<<<N_GRAPHS, 128, 0, stream>>>(gsum, gmax, gcnt, W1, b1, hidden);
    k_mlp2<<<N_GRAPHS, 32, 0, stream>>>(hidden, W2, b2, out);
}